// Round 1
// baseline (80.637 us; speedup 1.0000x reference)
//
#include <hip/hip_runtime.h>
#include <math.h>

// ---- fast hardware transcendentals (v_exp_f32 / v_log_f32 / v_sqrt_f32) ----
#if __has_builtin(__builtin_amdgcn_exp2f)
#define EXP2F __builtin_amdgcn_exp2f
#else
#define EXP2F exp2f
#endif
#if __has_builtin(__builtin_amdgcn_logf)
#define LOG2FF __builtin_amdgcn_logf
#else
#define LOG2FF log2f
#endif
#if __has_builtin(__builtin_amdgcn_sqrtf)
#define SQRTFF __builtin_amdgcn_sqrtf
#else
#define SQRTFF sqrtf
#endif

#define K_SMOOTH 32.0f
#define LOG2E 1.4426950408889634f
#define LN2 0.6931471805599453f
#define CLAMP_MIN 1e-6f
// -log(1e-6)/32 in fp32
#define FAR_OUT 0.43173470493638357f

constexpr int NS_MAX = 128;
constexpr int BLOCK = 256;
constexpr int CPTS = 8;                        // points scanned per thread
constexpr int PTS_PER_BLOCK = BLOCK * CPTS;    // 2048

__global__ __launch_bounds__(BLOCK) void smoothed_spheres_kernel(
    const float* __restrict__ p, const float* __restrict__ centers,
    const float* __restrict__ radii, const float* __restrict__ tfs,
    float* __restrict__ out, int n_pts, int n_spheres) {
  __shared__ float4 sph_ce[NS_MAX];      // cx, cy, cz, K*log2e*r
  __shared__ float  sph_T[NS_MAX][9];    // full T = tfs + I (general path)
  __shared__ int    queue[PTS_PER_BLOCK];
  __shared__ int    qcount;
  __shared__ float  redC[BLOCK / 64], redF[BLOCK / 64];
  __shared__ float  s_pthr2;             // squared norm threshold for "far"
  __shared__ int    s_ident;

  const int tid = threadIdx.x;
  const int ns = (n_spheres < NS_MAX) ? n_spheres : NS_MAX;

  // ---------------- Phase 0: per-sphere preprocessing (redundant per block) --
  float candC = 0.0f;  // ||c_i|| + r_i   (0 for inactive lanes is conservative)
  float candF = 0.0f;  // ||tfs_i||_F
  if (tid < ns) {
    const float cx = centers[3 * tid + 0];
    const float cy = centers[3 * tid + 1];
    const float cz = centers[3 * tid + 2];
    const float r = radii[tid];
    float fro = 0.0f;
#pragma unroll
    for (int j = 0; j < 9; ++j) {
      const float v = tfs[9 * tid + j];
      fro += v * v;
      sph_T[tid][j] = v + ((j == 0 || j == 4 || j == 8) ? 1.0f : 0.0f);
    }
    candC = SQRTFF(cx * cx + cy * cy + cz * cz) + r;
    candF = SQRTFF(fro);
    sph_ce[tid] = make_float4(cx, cy, cz, K_SMOOTH * LOG2E * r);
  }
  if (tid == 0) qcount = 0;

  // block max-reduce candC / candF
#pragma unroll
  for (int off = 32; off > 0; off >>= 1) {
    candC = fmaxf(candC, __shfl_xor(candC, off));
    candF = fmaxf(candF, __shfl_xor(candF, off));
  }
  if ((tid & 63) == 0) { redC[tid >> 6] = candC; redF[tid >> 6] = candF; }
  __syncthreads();
  if (tid == 0) {
    float Cmax = redC[0], Fmax = redF[0];
#pragma unroll
    for (int w = 1; w < BLOCK / 64; ++w) {
      Cmax = fmaxf(Cmax, redC[w]);
      Fmax = fmaxf(Fmax, redF[w]);
    }
    s_ident = (Fmax == 0.0f) ? 1 : 0;
    // need sd_min > ln(ns/1e-6)/32 (+ margin) for guaranteed clamp:
    const float sd_req = logf((float)(ns > 0 ? ns : 1) * 1e6f) * (1.0f / K_SMOOTH) + 0.01f;
    if (Fmax < 1.0f) {
      const float pthr = (Cmax + sd_req) / (1.0f - Fmax);
      s_pthr2 = pthr * pthr;
    } else {
      s_pthr2 = 3.0e38f;  // cannot prove anything far
    }
  }
  __syncthreads();

  // ---------------- Phase 1: scan; far -> write constant, near -> LDS queue --
  const int base = blockIdx.x * PTS_PER_BLOCK;
  const float pthr2 = s_pthr2;
#pragma unroll
  for (int j = 0; j < CPTS; ++j) {
    const int idx = base + j * BLOCK + tid;
    if (idx < n_pts) {
      const float px = p[3 * idx + 0];
      const float py = p[3 * idx + 1];
      const float pz = p[3 * idx + 2];
      const float pn2 = fmaf(px, px, fmaf(py, py, pz * pz));
      if (pn2 > pthr2) {
        out[idx] = FAR_OUT;
      } else {
        const int q = atomicAdd(&qcount, 1);
        queue[q] = idx;
      }
    }
  }
  __syncthreads();
  const int qn = qcount;

  // ---------------- Phase 2: full evaluation for queued (near) points -------
  if (s_ident) {
    // tfs == 0 exactly -> T = I -> q = p - c
    for (int qi = tid; qi < qn; qi += BLOCK) {
      const int idx = queue[qi];
      const float px = p[3 * idx + 0];
      const float py = p[3 * idx + 1];
      const float pz = p[3 * idx + 2];
      float s = 0.0f;
#pragma unroll 4
      for (int i = 0; i < ns; ++i) {
        const float4 c = sph_ce[i];
        const float dx = px - c.x;
        const float dy = py - c.y;
        const float dz = pz - c.z;
        const float d2 = fmaf(dx, dx, fmaf(dy, dy, dz * dz));
        const float nq = SQRTFF(d2);
        s += EXP2F(fmaf(nq, -K_SMOOTH * LOG2E, c.w));
      }
      s = fmaxf(s, CLAMP_MIN);
      out[idx] = -LOG2FF(s) * (LN2 / K_SMOOTH);
    }
  } else {
    // general path: q = T p - c
    for (int qi = tid; qi < qn; qi += BLOCK) {
      const int idx = queue[qi];
      const float px = p[3 * idx + 0];
      const float py = p[3 * idx + 1];
      const float pz = p[3 * idx + 2];
      float s = 0.0f;
      for (int i = 0; i < ns; ++i) {
        const float4 c = sph_ce[i];
        const float* T = sph_T[i];
        const float qx = fmaf(T[0], px, fmaf(T[1], py, fmaf(T[2], pz, -c.x)));
        const float qy = fmaf(T[3], px, fmaf(T[4], py, fmaf(T[5], pz, -c.y)));
        const float qz = fmaf(T[6], px, fmaf(T[7], py, fmaf(T[8], pz, -c.z)));
        const float d2 = fmaf(qx, qx, fmaf(qy, qy, qz * qz));
        const float nq = SQRTFF(d2);
        s += EXP2F(fmaf(nq, -K_SMOOTH * LOG2E, c.w));
      }
      s = fmaxf(s, CLAMP_MIN);
      out[idx] = -LOG2FF(s) * (LN2 / K_SMOOTH);
    }
  }
}

extern "C" void kernel_launch(void* const* d_in, const int* in_sizes, int n_in,
                              void* d_out, int out_size, void* d_ws, size_t ws_size,
                              hipStream_t stream) {
  const float* p = (const float*)d_in[0];
  const float* centers = (const float*)d_in[1];
  const float* radii = (const float*)d_in[2];
  const float* tfs = (const float*)d_in[3];
  float* out = (float*)d_out;

  const int n_pts = in_sizes[0] / 3;
  const int n_spheres = in_sizes[2];

  const int grid = (n_pts + PTS_PER_BLOCK - 1) / PTS_PER_BLOCK;
  smoothed_spheres_kernel<<<grid, BLOCK, 0, stream>>>(p, centers, radii, tfs,
                                                      out, n_pts, n_spheres);
}

// Round 2
// 74.649 us; speedup vs baseline: 1.0802x; 1.0802x over previous
//
#include <hip/hip_runtime.h>
#include <math.h>

// ---- fast hardware transcendentals (v_exp_f32 / v_log_f32 / v_sqrt_f32) ----
#if __has_builtin(__builtin_amdgcn_exp2f)
#define EXP2F __builtin_amdgcn_exp2f
#else
#define EXP2F exp2f
#endif
#if __has_builtin(__builtin_amdgcn_logf)
#define LOG2FF __builtin_amdgcn_logf
#else
#define LOG2FF log2f
#endif
#if __has_builtin(__builtin_amdgcn_sqrtf)
#define SQRTFF __builtin_amdgcn_sqrtf
#else
#define SQRTFF sqrtf
#endif

#define K_SMOOTH 32.0f
#define LOG2E 1.4426950408889634f
#define LN2 0.6931471805599453f
#define CLAMP_MIN 1e-6f
// -log(1e-6)/32 in fp32
#define FAR_OUT 0.43173470493638357f

constexpr int NS_MAX = 128;
constexpr int BLOCK = 256;
constexpr int CPTS = 4;                        // points scanned per thread
constexpr int PTS_PER_BLOCK = BLOCK * CPTS;    // 1024

__global__ __launch_bounds__(BLOCK) void smoothed_spheres_kernel(
    const float* __restrict__ p, const float* __restrict__ centers,
    const float* __restrict__ radii, const float* __restrict__ tfs,
    float* __restrict__ out, int n_pts, int n_spheres) {
  __shared__ float4 sph_ce[NS_MAX];      // cx, cy, cz, K*log2e*r
  __shared__ float  sph_T[NS_MAX][9];    // full T = tfs + I (general path)
  __shared__ float4 queue[PTS_PER_BLOCK];// px, py, pz, bitcast(idx)
  __shared__ int    qcount;
  __shared__ float  redC[BLOCK / 64], redF[BLOCK / 64];
  __shared__ float  s_pthr2;             // squared norm threshold for "far"
  __shared__ int    s_ident;

  const int tid = threadIdx.x;
  const int ns = (n_spheres < NS_MAX) ? n_spheres : NS_MAX;

  // ---------------- Phase 0: per-sphere preprocessing (redundant per block) --
  float candC = 0.0f;  // ||c_i|| + r_i   (0 for inactive lanes is conservative)
  float candF = 0.0f;  // ||tfs_i||_F
  if (tid < ns) {
    const float cx = centers[3 * tid + 0];
    const float cy = centers[3 * tid + 1];
    const float cz = centers[3 * tid + 2];
    const float r = radii[tid];
    float fro = 0.0f;
#pragma unroll
    for (int j = 0; j < 9; ++j) {
      const float v = tfs[9 * tid + j];
      fro += v * v;
      sph_T[tid][j] = v + ((j == 0 || j == 4 || j == 8) ? 1.0f : 0.0f);
    }
    candC = SQRTFF(cx * cx + cy * cy + cz * cz) + r;
    candF = SQRTFF(fro);
    sph_ce[tid] = make_float4(cx, cy, cz, K_SMOOTH * LOG2E * r);
  }
  if (tid == 0) qcount = 0;

  // block max-reduce candC / candF
#pragma unroll
  for (int off = 32; off > 0; off >>= 1) {
    candC = fmaxf(candC, __shfl_xor(candC, off));
    candF = fmaxf(candF, __shfl_xor(candF, off));
  }
  if ((tid & 63) == 0) { redC[tid >> 6] = candC; redF[tid >> 6] = candF; }
  __syncthreads();
  if (tid == 0) {
    float Cmax = redC[0], Fmax = redF[0];
#pragma unroll
    for (int w = 1; w < BLOCK / 64; ++w) {
      Cmax = fmaxf(Cmax, redC[w]);
      Fmax = fmaxf(Fmax, redF[w]);
    }
    s_ident = (Fmax == 0.0f) ? 1 : 0;
    // need sd_min > ln(ns/1e-6)/32 (+ margin) for guaranteed clamp:
    const float sd_req = logf((float)(ns > 0 ? ns : 1) * 1e6f) * (1.0f / K_SMOOTH) + 0.01f;
    if (Fmax < 1.0f) {
      const float pthr = (Cmax + sd_req) / (1.0f - Fmax);
      s_pthr2 = pthr * pthr;
    } else {
      s_pthr2 = 3.0e38f;  // cannot prove anything far
    }
  }
  __syncthreads();

  // ---------------- Phase 1: scan; far -> write constant, near -> LDS queue --
  const int base = blockIdx.x * PTS_PER_BLOCK;
  const float pthr2 = s_pthr2;
#pragma unroll
  for (int j = 0; j < CPTS; ++j) {
    const int idx = base + j * BLOCK + tid;
    if (idx < n_pts) {
      const float px = p[3 * idx + 0];
      const float py = p[3 * idx + 1];
      const float pz = p[3 * idx + 2];
      const float pn2 = fmaf(px, px, fmaf(py, py, pz * pz));
      if (pn2 > pthr2) {
        out[idx] = FAR_OUT;
      } else {
        const int q = atomicAdd(&qcount, 1);
        queue[q] = make_float4(px, py, pz, __int_as_float(idx));
      }
    }
  }
  __syncthreads();
  const int qn = qcount;

  // ---------------- Phase 2: full evaluation for queued (near) points -------
  if (s_ident) {
    // tfs == 0 exactly -> T = I -> q = p - c
    for (int qi = tid; qi < qn; qi += BLOCK) {
      const float4 e = queue[qi];
      const int idx = __float_as_int(e.w);
      const float px = e.x, py = e.y, pz = e.z;
      float s0 = 0.0f, s1 = 0.0f;
#pragma unroll 8
      for (int i = 0; i < ns; i += 2) {
        {
          const float4 c = sph_ce[i];
          const float dx = px - c.x;
          const float dy = py - c.y;
          const float dz = pz - c.z;
          const float d2 = fmaf(dx, dx, fmaf(dy, dy, dz * dz));
          s0 += EXP2F(fmaf(SQRTFF(d2), -K_SMOOTH * LOG2E, c.w));
        }
        {
          const float4 c = sph_ce[i + 1];
          const float dx = px - c.x;
          const float dy = py - c.y;
          const float dz = pz - c.z;
          const float d2 = fmaf(dx, dx, fmaf(dy, dy, dz * dz));
          s1 += EXP2F(fmaf(SQRTFF(d2), -K_SMOOTH * LOG2E, c.w));
        }
      }
      if (ns & 1) {
        const float4 c = sph_ce[ns - 1];
        const float dx = px - c.x;
        const float dy = py - c.y;
        const float dz = pz - c.z;
        const float d2 = fmaf(dx, dx, fmaf(dy, dy, dz * dz));
        s0 += EXP2F(fmaf(SQRTFF(d2), -K_SMOOTH * LOG2E, c.w));
      }
      const float s = fmaxf(s0 + s1, CLAMP_MIN);
      out[idx] = -LOG2FF(s) * (LN2 / K_SMOOTH);
    }
  } else {
    // general path: q = T p - c
    for (int qi = tid; qi < qn; qi += BLOCK) {
      const float4 e = queue[qi];
      const int idx = __float_as_int(e.w);
      const float px = e.x, py = e.y, pz = e.z;
      float s = 0.0f;
      for (int i = 0; i < ns; ++i) {
        const float4 c = sph_ce[i];
        const float* T = sph_T[i];
        const float qx = fmaf(T[0], px, fmaf(T[1], py, fmaf(T[2], pz, -c.x)));
        const float qy = fmaf(T[3], px, fmaf(T[4], py, fmaf(T[5], pz, -c.y)));
        const float qz = fmaf(T[6], px, fmaf(T[7], py, fmaf(T[8], pz, -c.z)));
        const float d2 = fmaf(qx, qx, fmaf(qy, qy, qz * qz));
        s += EXP2F(fmaf(SQRTFF(d2), -K_SMOOTH * LOG2E, c.w));
      }
      s = fmaxf(s, CLAMP_MIN);
      out[idx] = -LOG2FF(s) * (LN2 / K_SMOOTH);
    }
  }
}

extern "C" void kernel_launch(void* const* d_in, const int* in_sizes, int n_in,
                              void* d_out, int out_size, void* d_ws, size_t ws_size,
                              hipStream_t stream) {
  const float* p = (const float*)d_in[0];
  const float* centers = (const float*)d_in[1];
  const float* radii = (const float*)d_in[2];
  const float* tfs = (const float*)d_in[3];
  float* out = (float*)d_out;

  const int n_pts = in_sizes[0] / 3;
  const int n_spheres = in_sizes[2];

  const int grid = (n_pts + PTS_PER_BLOCK - 1) / PTS_PER_BLOCK;
  smoothed_spheres_kernel<<<grid, BLOCK, 0, stream>>>(p, centers, radii, tfs,
                                                      out, n_pts, n_spheres);
}